// Round 9
// baseline (426.496 us; speedup 1.0000x reference)
//
#include <hip/hip_runtime.h>
#include <hip/hip_fp16.h>
#include <math.h>

typedef _Float16 half8  __attribute__((ext_vector_type(8)));
typedef _Float16 half4v __attribute__((ext_vector_type(4)));
typedef float    f32x4  __attribute__((ext_vector_type(4)));

#define MFMA_F16 __builtin_amdgcn_mfma_f32_16x16x32_f16

namespace {

constexpr int M_ROWS = 64;                   // rows per block (4 waves x 64x64 tile)
// XOR-swizzled packed layouts (granule = 8 halves = 16 B):
//   Haddr(m,n) = m*256 + (((n>>3) ^ (m&7))<<3) + (n&7)     H: 64x256 = 32 KB
//   Paddr(m,k) = PE_OFF + m*64 + (((k>>3) ^ (m&7))<<3) + (k&7)   PE: 8 KB
// 40 KB/block. R9: R5 tile (only 3-wave/SIMD shape) + R2 explicit ping-pong
// fragment dbuf (in-wave load/MFMA overlap) + R7 SR addressing. MFMA-busy is
// pinned ~139us in R2-R8; wall = serialized MFMA+LDS+L1 pipes. dbuf x waves
// is the overlap mechanism.
constexpr int H_OFF      = 0;
constexpr int PE_OFF     = M_ROWS * 256;          // 16384 halves
constexpr int LDS_HALVES = PE_OFF + M_ROWS * 64;  // 20480 halves = 40960 B
constexpr size_t LDS_BYTES = (size_t)LDS_HALVES * sizeof(_Float16);

// Layer order: g1_0..g1_4, g2_0..g2_2, c_0, c_1, sig
constexpr int KCH_A[11] = {2,8,8,8,8,10,8,8,10,8,8};
constexpr int OFF_A[11] = {0,16384,81920,147456,212992,278528,360448,425984,491520,573440,577536};
constexpr int TOTAL_W   = 581632;   // fp16 elements in swizzled blob

struct Ptr11 { const float* p[11]; };

// ---------------------------------------------------------------------------
// Weight pre-swizzle (R7/R8 layout): ntile innermost so a K-chunk's 4 a-loads
// share one pointer with 1024 B immediate offsets:
//   256-out layers: blob[((kc*16 + ntile)*64 + lane)*8 + j]
//   heads (L=9,10): blob[(kc*64 + lane)*8 + j]
// Fragment semantics: W[remap(kc*32 + (lane>>4)*8 + j)][ntile*16 + (lane&15)]
// as fp16, 0 if padded (A-frag for mfma_f32_16x16x32_f16).
// ---------------------------------------------------------------------------
__global__ void prep_kernel(Ptr11 wp, _Float16* __restrict__ ws) {
  int tid = blockIdx.x * blockDim.x + threadIdx.x;
  if (tid >= TOTAL_W) return;
  int L = 0;
#pragma unroll
  for (int i = 1; i < 11; ++i) if (tid >= OFF_A[i]) L = i;
  int e    = tid - OFF_A[L];
  int j    = e & 7;
  int lane = (e >> 3) & 63;
  int blk  = e >> 9;
  int kc, nt;
  if (L <= 8) { kc = blk >> 4; nt = blk & 15; }
  else        { kc = blk;      nt = 0; }
  int kpad = kc * 32 + ((lane >> 4) << 3) + j;
  int n    = nt * 16 + (lane & 15);
  int k;
  if      (L == 0) k = (kpad < 63) ? kpad : -1;                               // g1_0: din 63 pad->64
  else if (L == 5) k = (kpad < 64) ? ((kpad < 63) ? kpad : -1) : kpad - 1;    // g2_0: [pe_x 63|f1 256]
  else if (L == 8) k = (kpad < 64) ? ((kpad < 39) ? kpad : -1) : kpad - 25;   // c_0:  [pe_d 39|f2 256]
  else             k = kpad;                                                  // din 256 exact
  int dout = (L == 9) ? 3 : ((L == 10) ? 1 : 256);
  float v = 0.f;
  if (k >= 0 && n < dout) v = wp.p[L][k * dout + n];
  ws[tid] = (_Float16)v;
}

// ---------------------------------------------------------------------------
// One 256-out linear layer; wave cg (0..3) computes rows [0,64) x cols
// [cg*64, cg*64+64). Explicit ping-pong dbuf (prefetch distance 1): loads of
// chunk k+1 issue before MFMAs of chunk k, all buffer indices compile-time
// (R1 lesson). Dual-base swizzle SR: (u^c1)*32 == u*32 + c1*32 (u even) or
// u*32 - c1*32 (u odd) -> every ds_read is base + literal offset.
// Budget: 64 AGPR acc + 64 frag + ~20 addr ~ 150-165 total -> 3 waves/SIMD
// under the (256,2) cap (no spill possible).
// ---------------------------------------------------------------------------
template <int PE_CH, int H_CH, bool RELU>
__device__ __forceinline__ void do_layer(_Float16* lds,
                                         const _Float16* __restrict__ blob,
                                         const float* __restrict__ bias,
                                         int cg, int lane) {
  constexpr int KCH = PE_CH + H_CH;
  const int l15  = lane & 15;
  const int quad = lane >> 4;
  const int s7   = l15 & 7;          // swizzle key (row&7 == l15&7)
  const int c1   = s7 >> 2;          // chunk-granule xor bit
  const int q3   = (quad ^ (s7 & 3));

  f32x4 acc[4][4];
#pragma unroll
  for (int mt = 0; mt < 4; ++mt)
#pragma unroll
    for (int nt = 0; nt < 4; ++nt) acc[mt][nt] = (f32x4)0.f;

  half8 aA[4], bA[4], aB[4], bB[4];

  const _Float16* ap = blob + ((size_t)(cg * 256 + lane)) * 8;
  const _Float16* pebase = lds + PE_OFF + l15 * 64 + q3 * 8;
  const _Float16* hbase  = lds + H_OFF  + l15 * 256 + q3 * 8;
  const int co = c1 << 5;            // 32-half parity correction
  const _Float16* peE = pebase + co;
  const _Float16* peO = pebase - co;
  const _Float16* hbE = hbase + co;
  const _Float16* hbO = hbase - co;

#define LOADF(ab, bb, KCG)                                                    \
  {                                                                           \
    const _Float16* apk = ap + (KCG) * 8192;                                  \
    _Pragma("unroll") for (int nt = 0; nt < 4; ++nt)                          \
        ab[nt] = *(const half8*)(apk + nt * 512);                             \
    if ((KCG) < PE_CH) {                                                      \
      const _Float16* bpp = (((KCG) & 1) ? peO : peE) + (KCG) * 32;           \
      _Pragma("unroll") for (int mt = 0; mt < 4; ++mt)                        \
          bb[mt] = *(const half8*)(bpp + mt * 1024);                          \
    } else {                                                                  \
      const int U = (KCG) - PE_CH;                                            \
      const _Float16* bpp = ((U & 1) ? hbO : hbE) + U * 32;                   \
      _Pragma("unroll") for (int mt = 0; mt < 4; ++mt)                        \
          bb[mt] = *(const half8*)(bpp + mt * 4096);                          \
    }                                                                         \
  }

#define DO_MFMA(ab, bb)                                                       \
  {                                                                           \
    _Pragma("unroll") for (int mt = 0; mt < 4; ++mt)                          \
        _Pragma("unroll") for (int nt = 0; nt < 4; ++nt)                      \
            acc[mt][nt] = MFMA_F16(ab[nt], bb[mt], acc[mt][nt], 0, 0, 0);     \
  }

  LOADF(aA, bA, 0)
#pragma unroll
  for (int kcg = 0; kcg < KCH; kcg += 2) {
    if (kcg + 1 < KCH) LOADF(aB, bB, kcg + 1)
    DO_MFMA(aA, bA)
    if (kcg + 2 < KCH) LOADF(aA, bA, kcg + 2)
    if (kcg + 1 < KCH) DO_MFMA(aB, bB)
  }
#undef LOADF
#undef DO_MFMA

  __syncthreads();   // all waves done READING H/PE before anyone overwrites H

  // Epilogue, SR: wa = mt*4096 + l15*256 + cg*64 + ((nt*2|qb)^s7)*8 + q1*4
  const int qb = quad >> 1, q1 = quad & 1;
  _Float16* wbase = lds + H_OFF + l15 * 256 + cg * 64 + q1 * 4;
  _Float16* wps[4] = { wbase + (((0 | qb) ^ s7) << 3),
                       wbase + (((2 | qb) ^ s7) << 3),
                       wbase + (((4 | qb) ^ s7) << 3),
                       wbase + (((6 | qb) ^ s7) << 3) };
#pragma unroll
  for (int mt = 0; mt < 4; ++mt) {
#pragma unroll
    for (int nt = 0; nt < 4; ++nt) {
      int n0 = cg * 64 + nt * 16 + quad * 4;
      f32x4 v = acc[mt][nt];
      f32x4 bb = *(const f32x4*)(bias + n0);
      v += bb;
      if (RELU) {
        v.x = fmaxf(v.x, 0.f); v.y = fmaxf(v.y, 0.f);
        v.z = fmaxf(v.z, 0.f); v.w = fmaxf(v.w, 0.f);
      }
      half4v hv = { (_Float16)v.x, (_Float16)v.y, (_Float16)v.z, (_Float16)v.w };
      *(half4v*)(wps[nt] + mt * 4096) = hv;
    }
  }
  __syncthreads();
}

// Head (sig / c_1): NT=1 blob, K=256 over H; wave w covers rows [w*16,w*16+16).
__device__ __forceinline__ f32x4 head_mt(const _Float16* lds,
                                         const _Float16* __restrict__ blob,
                                         int w, int lane) {
  const int l15  = lane & 15;
  const int quad = lane >> 4;
  const int s7   = l15 & 7;
  const int c1   = s7 >> 2;
  const int q3   = (quad ^ (s7 & 3));
  const _Float16* hb = lds + H_OFF + (w * 16 + l15) * 256 + q3 * 8;
  f32x4 res = (f32x4)0.f;
#pragma unroll
  for (int kc = 0; kc < 8; ++kc) {
    half8 a = *(const half8*)(blob + (kc * 64 + lane) * 8);
    half8 b = *(const half8*)(hb + ((kc ^ c1) << 5));
    res = MFMA_F16(a, b, res, 0, 0, 0);
  }
  return res;
}

// Positional encoding: f = tid&63 loop-invariant -> classify once per thread.
// __sinf/__cosf: abs err ~1.5e-4, well under the f16 storage rounding.
__device__ __forceinline__ void pe_pass(_Float16* lds, const float* __restrict__ src,
                                        int row0, int tid, int nfeat) {
  const int f  = tid & 63;
  const int rb = tid >> 6;
  const int fg = f >> 3, f7 = f & 7;
  int mode, c = 0, use_cos = 0;
  float freq = 0.f;
  if (f < 3) { mode = 0; c = f; }
  else if (f < nfeat) {
    int g = f - 3, li = g / 6, rem = g - li * 6;
    use_cos = (rem >= 3); c = use_cos ? rem - 3 : rem;
    freq = (float)(1 << li); mode = 1;
  } else mode = 2;
#pragma unroll
  for (int t = 0; t < 16; ++t) {
    int r = rb + t * 4;
    float v = 0.f;
    if (mode == 0) v = src[(row0 + r) * 3 + c];
    else if (mode == 1) {
      float a = src[(row0 + r) * 3 + c] * freq;
      v = use_cos ? __cosf(a) : __sinf(a);
    }
    lds[PE_OFF + r * 64 + (((fg ^ (r & 7)) << 3) | f7)] = (_Float16)v;
  }
}

__global__ __launch_bounds__(256, 2) void nerf_kernel(
    const _Float16* __restrict__ ws, const float* __restrict__ x,
    const float* __restrict__ dirp, Ptr11 bp, float* __restrict__ out) {
  extern __shared__ _Float16 lds[];
  const int tid  = threadIdx.x;
  const int lane = tid & 63;
  const int w    = tid >> 6;       // wave 0..3 (= col-group cg)
  const int l15  = lane & 15;
  const int quad = lane >> 4;
  const int row0 = blockIdx.x * M_ROWS;

  // ---- pe_x -> PE buffer ----
  pe_pass(lds, x, row0, tid, 63);
  __syncthreads();

  // ---- G1: 63->256, 256->256 x4 (ReLU on all but last) ----
  do_layer<2, 0, true >(lds, ws + OFF_A[0], bp.p[0], w, lane);
  do_layer<0, 8, true >(lds, ws + OFF_A[1], bp.p[1], w, lane);
  do_layer<0, 8, true >(lds, ws + OFF_A[2], bp.p[2], w, lane);
  do_layer<0, 8, true >(lds, ws + OFF_A[3], bp.p[3], w, lane);
  do_layer<0, 8, false>(lds, ws + OFF_A[4], bp.p[4], w, lane);  // f1
  // ---- G2: [pe_x|f1] -> 256, 256->256, 256->256 (no ReLU on last) ----
  do_layer<2, 8, true >(lds, ws + OFF_A[5], bp.p[5], w, lane);  // pe_x last use
  do_layer<0, 8, true >(lds, ws + OFF_A[6], bp.p[6], w, lane);
  do_layer<0, 8, false>(lds, ws + OFF_A[7], bp.p[7], w, lane);  // f2

  // ---- sigma head: wave w covers rows [w*16, w*16+16) (reads f2 in H) ----
  f32x4 sa = head_mt(lds, ws + OFF_A[10], w, lane);
  float sigv = sa[0] + bp.p[10][0];   // valid in quad==0 lanes

  // ---- pe_d recompute into PE buffer (pe_x dead after g2_0) ----
  pe_pass(lds, dirp, row0, tid, 39);
  __syncthreads();   // PE writes visible; sig reads done (barrier covers both)

  // ---- color: [pe_d|f2] -> 256 (ReLU), then 256 -> 3 ----
  do_layer<2, 8, true>(lds, ws + OFF_A[8], bp.p[8], w, lane);
  f32x4 ca = head_mt(lds, ws + OFF_A[9], w, lane);
  if (quad == 0) {
    f32x4 o = { ca[0] + bp.p[9][0], ca[1] + bp.p[9][1], ca[2] + bp.p[9][2], sigv };
    *(f32x4*)(out + (size_t)(row0 + w * 16 + l15) * 4) = o;
  }
}

}  // namespace

extern "C" void kernel_launch(void* const* d_in, const int* in_sizes, int n_in,
                              void* d_out, int out_size, void* d_ws, size_t ws_size,
                              hipStream_t stream) {
  const float* x   = (const float*)d_in[0];
  const float* dir = (const float*)d_in[1];
  Ptr11 wp, bp;
  for (int i = 0; i < 11; ++i) {
    wp.p[i] = (const float*)d_in[2 + 2 * i];
    bp.p[i] = (const float*)d_in[3 + 2 * i];
  }
  _Float16* ws = (_Float16*)d_ws;
  float* out = (float*)d_out;

  hipFuncSetAttribute((const void*)nerf_kernel,
                      hipFuncAttributeMaxDynamicSharedMemorySize, (int)LDS_BYTES);

  prep_kernel<<<TOTAL_W / 256, 256, 0, stream>>>(wp, ws);
  nerf_kernel<<<262144 / M_ROWS, 256, LDS_BYTES, stream>>>(ws, x, dir, bp, out);
}